// Round 1
// baseline (159.298 us; speedup 1.0000x reference)
//
#include <hip/hip_runtime.h>
#include <math.h>

// Problem constants (fixed by the reference)
#define NN   4096      // nodes per graph
#define EE   32768     // edges per graph (unique; B tiled copies are identical)
#define NB   4         // batch
#define ACc  16
#define UCc  16
#define INC  32        // AC+UC
#define OUTC 32
#define HID  8
#define EDGEC 68

__device__ __forceinline__ float gelu_exact(float v) {
    // jax.nn.gelu(approximate=False): x * 0.5 * (1 + erf(x/sqrt(2)))
    return 0.5f * v * (1.0f + erff(v * 0.70710678118654752f));
}

// ---------------------------------------------------------------------------
// Kernel A: per-node precompute.
//   hs[n][k] = b1[k] + sum_j pw[n][j]   * w1[k*68 + j]      (j < 34, src half)
//   hd[n][k] =         sum_j pw[n][j]   * w1[k*68 + 34 + j] (dst half)
//   G[n][o][k] = sum_i x[n][i] * w2[(i*32+o)*8 + k]
//   bbx[n][o]  = sum_i x[n][i] * b2[i*32+o]
// rec layout per node: 256 floats of G (o-major, k inner) then 32 floats bbx.
// One thread per (n, o): 512 blocks x 256 threads.
// ---------------------------------------------------------------------------
__global__ __launch_bounds__(256) void node_pre_kernel(
    const float* __restrict__ a, const float* __restrict__ u,
    const float* __restrict__ gpos,
    const float* __restrict__ w1, const float* __restrict__ b1,
    const float* __restrict__ w2, const float* __restrict__ b2,
    float* __restrict__ hs, float* __restrict__ hd, float* __restrict__ rec)
{
    __shared__ float w2s[INC * OUTC * HID];   // 8192
    __shared__ float w1s[HID * EDGEC];        // 544
    __shared__ float b2s[INC * OUTC];         // 1024
    __shared__ float b1s[HID];

    for (int i = threadIdx.x; i < INC * OUTC * HID; i += 256) w2s[i] = w2[i];
    for (int i = threadIdx.x; i < HID * EDGEC; i += 256)      w1s[i] = w1[i];
    for (int i = threadIdx.x; i < INC * OUTC; i += 256)       b2s[i] = b2[i];
    if (threadIdx.x < HID) b1s[threadIdx.x] = b1[threadIdx.x];
    __syncthreads();

    int t = blockIdx.x * 256 + threadIdx.x;   // t in [0, 4096*32)
    int n = t >> 5;
    int o = t & 31;

    // load x[n] (batch-0 features): a[0,c,n] then u[0,c,n]
    float x[INC];
    #pragma unroll
    for (int c = 0; c < ACc; ++c) x[c] = a[c * NN + n];
    #pragma unroll
    for (int c = 0; c < UCc; ++c) x[ACc + c] = u[c * NN + n];

    // G row for this o, plus bbx
    float g[HID];
    #pragma unroll
    for (int k = 0; k < HID; ++k) g[k] = 0.0f;
    float bb = 0.0f;
    #pragma unroll
    for (int i = 0; i < INC; ++i) {
        float xi = x[i];
        int r = i * OUTC + o;
        const float* wp = &w2s[r * HID];
        #pragma unroll
        for (int k = 0; k < HID; ++k) g[k] += xi * wp[k];
        bb += xi * b2s[r];
    }
    float* rp = rec + (size_t)n * 288;
    #pragma unroll
    for (int k = 0; k < HID; ++k) rp[o * HID + k] = g[k];
    rp[256 + o] = bb;

    // hs / hd: threads o<8 do hs[k=o], threads 8..15 do hd[k=o-8]
    if (o < 16) {
        int k = o & 7;
        bool dsth = (o >= 8);
        int base = k * EDGEC + (dsth ? 34 : 0);
        float hv = dsth ? 0.0f : b1s[k];
        #pragma unroll
        for (int c = 0; c < INC; ++c) hv += x[c] * w1s[base + c];
        hv += gpos[n * 2 + 0] * w1s[base + 32];
        hv += gpos[n * 2 + 1] * w1s[base + 33];
        (dsth ? hd : hs)[n * HID + k] = hv;
    }
}

// ---------------------------------------------------------------------------
// Kernel B (fast path): one thread per edge.
//   h = gelu(hs[s] + hd[d]);  msg[o] = bbx[s][o] + sum_k h[k]*G[s][o][k]
//   atomicAdd into agg[d*32+o], cnt[d].
// ---------------------------------------------------------------------------
__global__ __launch_bounds__(64) void edge_fast_kernel(
    const int* __restrict__ ei,
    const float* __restrict__ hs, const float* __restrict__ hd,
    const float* __restrict__ rec,
    float* __restrict__ agg, float* __restrict__ cnt)
{
    int e = blockIdx.x * 64 + threadIdx.x;
    if (e >= EE) return;
    int s = ei[e];
    int d = ei[EE + e];

    const float4* hsp = (const float4*)(hs + s * HID);
    const float4* hdp = (const float4*)(hd + d * HID);
    float4 s0 = hsp[0], s1 = hsp[1];
    float4 d0 = hdp[0], d1 = hdp[1];
    float h[HID];
    h[0] = gelu_exact(s0.x + d0.x); h[1] = gelu_exact(s0.y + d0.y);
    h[2] = gelu_exact(s0.z + d0.z); h[3] = gelu_exact(s0.w + d0.w);
    h[4] = gelu_exact(s1.x + d1.x); h[5] = gelu_exact(s1.y + d1.y);
    h[6] = gelu_exact(s1.z + d1.z); h[7] = gelu_exact(s1.w + d1.w);

    const float* rp = rec + (size_t)s * 288;
    float* aggd = agg + d * OUTC;
    #pragma unroll 4
    for (int o = 0; o < OUTC; ++o) {
        const float4* gp = (const float4*)(rp + o * HID);
        float4 g0 = gp[0], g1 = gp[1];
        float m = rp[256 + o]
                + h[0] * g0.x + h[1] * g0.y + h[2] * g0.z + h[3] * g0.w
                + h[4] * g1.x + h[5] * g1.y + h[6] * g1.z + h[7] * g1.w;
        atomicAdd(aggd + o, m);
    }
    atomicAdd(cnt + d, 1.0f);
}

// ---------------------------------------------------------------------------
// Kernel B' (fallback if ws too small): self-contained per-edge compute.
// ---------------------------------------------------------------------------
__global__ __launch_bounds__(256) void edge_slow_kernel(
    const float* __restrict__ a, const float* __restrict__ u,
    const float* __restrict__ gpos, const int* __restrict__ ei,
    const float* __restrict__ w1, const float* __restrict__ b1,
    const float* __restrict__ w2, const float* __restrict__ b2,
    float* __restrict__ agg, float* __restrict__ cnt)
{
    __shared__ float w1s[HID * EDGEC];
    __shared__ float b1s[HID];
    __shared__ float w2s[INC * OUTC * HID];
    __shared__ float b2s[INC * OUTC];
    for (int i = threadIdx.x; i < HID * EDGEC; i += 256)      w1s[i] = w1[i];
    for (int i = threadIdx.x; i < INC * OUTC * HID; i += 256) w2s[i] = w2[i];
    for (int i = threadIdx.x; i < INC * OUTC; i += 256)       b2s[i] = b2[i];
    if (threadIdx.x < HID) b1s[threadIdx.x] = b1[threadIdx.x];
    __syncthreads();

    int e = blockIdx.x * 256 + threadIdx.x;
    if (e >= EE) return;
    int s = ei[e];
    int d = ei[EE + e];

    float h[HID];
    #pragma unroll
    for (int k = 0; k < HID; ++k) h[k] = b1s[k];
    float xs[INC];

    #pragma unroll
    for (int c = 0; c < ACc; ++c) {
        float v = a[c * NN + s]; xs[c] = v;
        #pragma unroll
        for (int k = 0; k < HID; ++k) h[k] += v * w1s[k * EDGEC + c];
    }
    #pragma unroll
    for (int c = 0; c < UCc; ++c) {
        float v = u[c * NN + s]; xs[ACc + c] = v;
        #pragma unroll
        for (int k = 0; k < HID; ++k) h[k] += v * w1s[k * EDGEC + ACc + c];
    }
    {
        float v0 = gpos[s * 2], v1 = gpos[s * 2 + 1];
        #pragma unroll
        for (int k = 0; k < HID; ++k)
            h[k] += v0 * w1s[k * EDGEC + 32] + v1 * w1s[k * EDGEC + 33];
    }
    #pragma unroll
    for (int c = 0; c < ACc; ++c) {
        float v = a[c * NN + d];
        #pragma unroll
        for (int k = 0; k < HID; ++k) h[k] += v * w1s[k * EDGEC + 34 + c];
    }
    #pragma unroll
    for (int c = 0; c < UCc; ++c) {
        float v = u[c * NN + d];
        #pragma unroll
        for (int k = 0; k < HID; ++k) h[k] += v * w1s[k * EDGEC + 50 + c];
    }
    {
        float v0 = gpos[d * 2], v1 = gpos[d * 2 + 1];
        #pragma unroll
        for (int k = 0; k < HID; ++k)
            h[k] += v0 * w1s[k * EDGEC + 66] + v1 * w1s[k * EDGEC + 67];
    }
    #pragma unroll
    for (int k = 0; k < HID; ++k) h[k] = gelu_exact(h[k]);

    float* aggd = agg + d * OUTC;
    for (int o = 0; o < OUTC; ++o) {
        float m = 0.0f;
        #pragma unroll 4
        for (int i = 0; i < INC; ++i) {
            int r = i * OUTC + o;
            float wv = b2s[r];
            const float* wp = &w2s[r * HID];
            #pragma unroll
            for (int k = 0; k < HID; ++k) wv += h[k] * wp[k];
            m += xs[i] * wv;
        }
        atomicAdd(aggd + o, m);
    }
    atomicAdd(cnt + d, 1.0f);
}

// ---------------------------------------------------------------------------
// Kernel C: output.  out[b,o,n] = (b==0 ? agg[n,o]/max(cnt,1) : 0)
//                                + sum_i x[b,n,i]*root[i,o]
// ---------------------------------------------------------------------------
__global__ __launch_bounds__(64) void out_kernel(
    const float* __restrict__ a, const float* __restrict__ u,
    const float* __restrict__ root,
    const float* __restrict__ agg, const float* __restrict__ cnt,
    float* __restrict__ out)
{
    __shared__ float rs[INC * OUTC];
    for (int i = threadIdx.x; i < INC * OUTC; i += 64) rs[i] = root[i];
    __syncthreads();

    int idx = blockIdx.x * 64 + threadIdx.x;   // [0, NB*NN)
    int b = idx >> 12;
    int n = idx & (NN - 1);

    float x[INC];
    #pragma unroll
    for (int c = 0; c < ACc; ++c) x[c] = a[(b * ACc + c) * NN + n];
    #pragma unroll
    for (int c = 0; c < UCc; ++c) x[ACc + c] = u[(b * UCc + c) * NN + n];

    bool first = (b == 0);
    float inv = 0.0f;
    if (first) inv = 1.0f / fmaxf(cnt[n], 1.0f);

    for (int o = 0; o < OUTC; ++o) {
        float v = first ? agg[n * OUTC + o] * inv : 0.0f;
        #pragma unroll
        for (int i = 0; i < INC; ++i) v += x[i] * rs[i * OUTC + o];
        out[(b * OUTC + o) * NN + n] = v;
    }
}

extern "C" void kernel_launch(void* const* d_in, const int* in_sizes, int n_in,
                              void* d_out, int out_size, void* d_ws, size_t ws_size,
                              hipStream_t stream) {
    const float* a    = (const float*)d_in[0];
    const float* u    = (const float*)d_in[1];
    const float* gpos = (const float*)d_in[2];
    const int*   ei   = (const int*)d_in[3];
    const float* w1   = (const float*)d_in[4];
    const float* b1   = (const float*)d_in[5];
    const float* w2   = (const float*)d_in[6];
    const float* b2   = (const float*)d_in[7];
    const float* root = (const float*)d_in[8];
    float* out = (float*)d_out;

    // workspace layout (floats):
    //   agg: [0, 131072)  cnt: [131072, 135168)
    //   hs:  [135168, +32768)  hd: [167936, +32768)  rec: [200704, +4096*288)
    float* ws  = (float*)d_ws;
    float* agg = ws;
    float* cnt = ws + NN * OUTC;
    hipMemsetAsync(d_ws, 0, (size_t)(NN * OUTC + NN) * sizeof(float), stream);

    const size_t need = (size_t)(200704 + NN * 288) * sizeof(float);  // 5.52 MB
    if (ws_size >= need) {
        float* hs  = ws + 135168;
        float* hd  = ws + 167936;
        float* rec = ws + 200704;
        node_pre_kernel<<<(NN * 32) / 256, 256, 0, stream>>>(
            a, u, gpos, w1, b1, w2, b2, hs, hd, rec);
        edge_fast_kernel<<<EE / 64, 64, 0, stream>>>(ei, hs, hd, rec, agg, cnt);
    } else {
        edge_slow_kernel<<<EE / 256, 256, 0, stream>>>(
            a, u, gpos, ei, w1, b1, w2, b2, agg, cnt);
    }
    out_kernel<<<(NB * NN) / 64, 64, 0, stream>>>(a, u, root, agg, cnt, out);
}

// Round 2
// 106.083 us; speedup vs baseline: 1.5016x; 1.5016x over previous
//
#include <hip/hip_runtime.h>
#include <math.h>

// Problem constants (fixed by the reference)
#define NN   4096      // nodes per graph
#define EE   32768     // edges per graph (unique; B tiled copies are identical)
#define NB   4         // batch
#define ACc  16
#define UCc  16
#define INC  32        // AC+UC
#define OUTC 32
#define HID  8
#define EDGEC 68

__device__ __forceinline__ float gelu_exact(float v) {
    // jax.nn.gelu(approximate=False): x * 0.5 * (1 + erf(x/sqrt(2)))
    return 0.5f * v * (1.0f + erff(v * 0.70710678118654752f));
}

// ---------------------------------------------------------------------------
// Kernel A (fused): blocks [0,512): per-node precompute; blocks [512,640):
// destination histogram into icnt.
//   hs[n][k] = b1[k] + sum_j pw[n][j] * w1[k*68 + j]       (src half, j<34)
//   hd[n][k] =         sum_j pw[n][j] * w1[k*68 + 34 + j]  (dst half)
//   G[n][o][k] = sum_i x[n][i] * w2[(i*32+o)*8 + k]
//   bbx[n][o]  = sum_i x[n][i] * b2[i*32+o]
// rec layout per node: 256 floats G (o-major, k inner) then 32 floats bbx.
// ---------------------------------------------------------------------------
__global__ __launch_bounds__(256) void node_hist_kernel(
    const float* __restrict__ a, const float* __restrict__ u,
    const float* __restrict__ gpos, const int* __restrict__ ei,
    const float* __restrict__ w1, const float* __restrict__ b1,
    const float* __restrict__ w2, const float* __restrict__ b2,
    float* __restrict__ hs, float* __restrict__ hd, float* __restrict__ rec,
    int* __restrict__ icnt)
{
    if (blockIdx.x >= 512) {
        int e = (blockIdx.x - 512) * 256 + threadIdx.x;   // < EE (128 blocks)
        atomicAdd(&icnt[ei[EE + e]], 1);
        return;
    }

    __shared__ float w2s[INC * OUTC * HID];   // 8192
    __shared__ float w1s[HID * EDGEC];        // 544
    __shared__ float b2s[INC * OUTC];         // 1024
    __shared__ float b1s[HID];

    for (int i = threadIdx.x; i < INC * OUTC * HID; i += 256) w2s[i] = w2[i];
    for (int i = threadIdx.x; i < HID * EDGEC; i += 256)      w1s[i] = w1[i];
    for (int i = threadIdx.x; i < INC * OUTC; i += 256)       b2s[i] = b2[i];
    if (threadIdx.x < HID) b1s[threadIdx.x] = b1[threadIdx.x];
    __syncthreads();

    int t = blockIdx.x * 256 + threadIdx.x;   // [0, 4096*32)
    int n = t >> 5;
    int o = t & 31;

    float x[INC];
    #pragma unroll
    for (int c = 0; c < ACc; ++c) x[c] = a[c * NN + n];
    #pragma unroll
    for (int c = 0; c < UCc; ++c) x[ACc + c] = u[c * NN + n];

    float g[HID];
    #pragma unroll
    for (int k = 0; k < HID; ++k) g[k] = 0.0f;
    float bb = 0.0f;
    #pragma unroll
    for (int i = 0; i < INC; ++i) {
        float xi = x[i];
        int r = i * OUTC + o;
        const float* wp = &w2s[r * HID];
        #pragma unroll
        for (int k = 0; k < HID; ++k) g[k] += xi * wp[k];
        bb += xi * b2s[r];
    }
    float* rp = rec + (size_t)n * 288;
    #pragma unroll
    for (int k = 0; k < HID; ++k) rp[o * HID + k] = g[k];
    rp[256 + o] = bb;

    if (o < 16) {
        int k = o & 7;
        bool dsth = (o >= 8);
        int base = k * EDGEC + (dsth ? 34 : 0);
        float hv = dsth ? 0.0f : b1s[k];
        #pragma unroll
        for (int c = 0; c < INC; ++c) hv += x[c] * w1s[base + c];
        hv += gpos[n * 2 + 0] * w1s[base + 32];
        hv += gpos[n * 2 + 1] * w1s[base + 33];
        (dsth ? hd : hs)[n * HID + k] = hv;
    }
}

// ---------------------------------------------------------------------------
// Kernel B: exclusive scan of icnt[4096] -> rowptr[4097], woff[4096].
// Single block, 256 threads x 16 elements each.
// ---------------------------------------------------------------------------
__global__ __launch_bounds__(256) void scan_kernel(
    const int* __restrict__ icnt, int* __restrict__ rowptr,
    int* __restrict__ woff)
{
    __shared__ int part[256];
    int tid = threadIdx.x;
    int base = tid * 16;
    int v[16];
    int s = 0;
    #pragma unroll
    for (int j = 0; j < 16; ++j) {
        int t = icnt[base + j];
        v[j] = s;          // exclusive prefix within chunk
        s += t;
    }
    part[tid] = s;
    __syncthreads();
    for (int off = 1; off < 256; off <<= 1) {
        int t = (tid >= off) ? part[tid - off] : 0;
        __syncthreads();
        part[tid] += t;
        __syncthreads();
    }
    int chunkbase = (tid > 0) ? part[tid - 1] : 0;
    #pragma unroll
    for (int j = 0; j < 16; ++j) {
        int r = chunkbase + v[j];
        rowptr[base + j] = r;
        woff[base + j] = r;
    }
    if (tid == 255) rowptr[NN] = part[255];
}

// ---------------------------------------------------------------------------
// Kernel C: scatter edges into CSR src-list.
// ---------------------------------------------------------------------------
__global__ __launch_bounds__(256) void scatter_kernel(
    const int* __restrict__ ei, int* __restrict__ woff,
    int* __restrict__ slist)
{
    int e = blockIdx.x * 256 + threadIdx.x;   // < EE
    int s = ei[e];
    int d = ei[EE + e];
    int pos = atomicAdd(&woff[d], 1);
    slist[pos] = s;
}

// ---------------------------------------------------------------------------
// Kernel D: destination-centric gather. One wave per destination.
// lane = tid&63; p = lane>>5 (edge pair slot); o = lane&31 (output channel).
//   h = gelu(hs[s] + hd[d]);  msg[o] = bbx[s][o] + sum_k h[k]*G[s][o][k]
// acc over this dest's edges, pair-reduce, write MEAN to agg (plain store).
// ---------------------------------------------------------------------------
__global__ __launch_bounds__(256) void gather_kernel(
    const int* __restrict__ rowptr, const int* __restrict__ slist,
    const float* __restrict__ hs, const float* __restrict__ hd,
    const float* __restrict__ rec, float* __restrict__ agg)
{
    int wave = blockIdx.x * 4 + (threadIdx.x >> 6);   // destination node d
    int d = wave;
    int lane = threadIdx.x & 63;
    int p = lane >> 5;
    int o = lane & 31;

    int start = rowptr[d];
    int end   = rowptr[d + 1];

    float hdk = 0.0f;
    if (o < HID) hdk = hd[d * HID + o];

    float acc = 0.0f;
    for (int j = start + p; j < end; j += 2) {
        int s = slist[j];
        float hval = 0.0f;
        if (o < HID) hval = gelu_exact(hs[s * HID + o] + hdk);
        int sb = p << 5;
        float h0 = __shfl(hval, sb + 0, 64);
        float h1 = __shfl(hval, sb + 1, 64);
        float h2 = __shfl(hval, sb + 2, 64);
        float h3 = __shfl(hval, sb + 3, 64);
        float h4 = __shfl(hval, sb + 4, 64);
        float h5 = __shfl(hval, sb + 5, 64);
        float h6 = __shfl(hval, sb + 6, 64);
        float h7 = __shfl(hval, sb + 7, 64);

        const float* rp = rec + (size_t)s * 288;
        const float4* gp = (const float4*)(rp + o * HID);
        float4 g0 = gp[0], g1 = gp[1];
        float m = rp[256 + o]
                + h0 * g0.x + h1 * g0.y + h2 * g0.z + h3 * g0.w
                + h4 * g1.x + h5 * g1.y + h6 * g1.z + h7 * g1.w;
        acc += m;
    }
    acc += __shfl_xor(acc, 32, 64);
    if (p == 0) {
        float c = (float)(end - start);
        agg[d * OUTC + o] = acc / fmaxf(c, 1.0f);
    }
}

// ---------------------------------------------------------------------------
// Kernel E: output. blockIdx -> (b, o-quad, n-chunk). agg already holds mean.
//   out[b,o,n] = (b==0 ? agg[n,o] : 0) + sum_i x[b,n,i]*root[i,o]
// ---------------------------------------------------------------------------
__global__ __launch_bounds__(256) void out_kernel(
    const float* __restrict__ a, const float* __restrict__ u,
    const float* __restrict__ root, const float* __restrict__ agg,
    float* __restrict__ out)
{
    __shared__ float rs[INC * OUTC];
    for (int i = threadIdx.x; i < INC * OUTC; i += 256) rs[i] = root[i];
    __syncthreads();

    int b     = blockIdx.x >> 7;          // 4
    int rem   = blockIdx.x & 127;
    int oq    = rem >> 4;                 // 8 o-quads
    int chunk = rem & 15;                 // 16 n-chunks
    int n = chunk * 256 + threadIdx.x;

    float x[INC];
    #pragma unroll
    for (int c = 0; c < ACc; ++c) x[c] = a[(b * ACc + c) * NN + n];
    #pragma unroll
    for (int c = 0; c < UCc; ++c) x[ACc + c] = u[(b * UCc + c) * NN + n];

    bool first = (b == 0);
    #pragma unroll
    for (int q = 0; q < 4; ++q) {
        int o = oq * 4 + q;
        float v = first ? agg[n * OUTC + o] : 0.0f;
        #pragma unroll
        for (int i = 0; i < INC; ++i) v += x[i] * rs[i * OUTC + o];
        out[(b * OUTC + o) * NN + n] = v;
    }
}

// ---------------------------------------------------------------------------
// Fallback kernels (workspace too small): R0 slow path.
// ---------------------------------------------------------------------------
__global__ __launch_bounds__(256) void edge_slow_kernel(
    const float* __restrict__ a, const float* __restrict__ u,
    const float* __restrict__ gpos, const int* __restrict__ ei,
    const float* __restrict__ w1, const float* __restrict__ b1,
    const float* __restrict__ w2, const float* __restrict__ b2,
    float* __restrict__ agg, float* __restrict__ cnt)
{
    __shared__ float w1s[HID * EDGEC];
    __shared__ float b1s[HID];
    __shared__ float w2s[INC * OUTC * HID];
    __shared__ float b2s[INC * OUTC];
    for (int i = threadIdx.x; i < HID * EDGEC; i += 256)      w1s[i] = w1[i];
    for (int i = threadIdx.x; i < INC * OUTC * HID; i += 256) w2s[i] = w2[i];
    for (int i = threadIdx.x; i < INC * OUTC; i += 256)       b2s[i] = b2[i];
    if (threadIdx.x < HID) b1s[threadIdx.x] = b1[threadIdx.x];
    __syncthreads();

    int e = blockIdx.x * 256 + threadIdx.x;
    if (e >= EE) return;
    int s = ei[e];
    int d = ei[EE + e];

    float h[HID];
    #pragma unroll
    for (int k = 0; k < HID; ++k) h[k] = b1s[k];
    float xs[INC];

    #pragma unroll
    for (int c = 0; c < ACc; ++c) {
        float v = a[c * NN + s]; xs[c] = v;
        #pragma unroll
        for (int k = 0; k < HID; ++k) h[k] += v * w1s[k * EDGEC + c];
    }
    #pragma unroll
    for (int c = 0; c < UCc; ++c) {
        float v = u[c * NN + s]; xs[ACc + c] = v;
        #pragma unroll
        for (int k = 0; k < HID; ++k) h[k] += v * w1s[k * EDGEC + ACc + c];
    }
    {
        float v0 = gpos[s * 2], v1 = gpos[s * 2 + 1];
        #pragma unroll
        for (int k = 0; k < HID; ++k)
            h[k] += v0 * w1s[k * EDGEC + 32] + v1 * w1s[k * EDGEC + 33];
    }
    #pragma unroll
    for (int c = 0; c < ACc; ++c) {
        float v = a[c * NN + d];
        #pragma unroll
        for (int k = 0; k < HID; ++k) h[k] += v * w1s[k * EDGEC + 34 + c];
    }
    #pragma unroll
    for (int c = 0; c < UCc; ++c) {
        float v = u[c * NN + d];
        #pragma unroll
        for (int k = 0; k < HID; ++k) h[k] += v * w1s[k * EDGEC + 50 + c];
    }
    {
        float v0 = gpos[d * 2], v1 = gpos[d * 2 + 1];
        #pragma unroll
        for (int k = 0; k < HID; ++k)
            h[k] += v0 * w1s[k * EDGEC + 66] + v1 * w1s[k * EDGEC + 67];
    }
    #pragma unroll
    for (int k = 0; k < HID; ++k) h[k] = gelu_exact(h[k]);

    float* aggd = agg + d * OUTC;
    for (int o = 0; o < OUTC; ++o) {
        float m = 0.0f;
        #pragma unroll 4
        for (int i = 0; i < INC; ++i) {
            int r = i * OUTC + o;
            float wv = b2s[r];
            const float* wp = &w2s[r * HID];
            #pragma unroll
            for (int k = 0; k < HID; ++k) wv += h[k] * wp[k];
            m += xs[i] * wv;
        }
        atomicAdd(aggd + o, m);
    }
    atomicAdd(cnt + d, 1.0f);
}

__global__ __launch_bounds__(64) void out_fallback_kernel(
    const float* __restrict__ a, const float* __restrict__ u,
    const float* __restrict__ root,
    const float* __restrict__ agg, const float* __restrict__ cnt,
    float* __restrict__ out)
{
    __shared__ float rs[INC * OUTC];
    for (int i = threadIdx.x; i < INC * OUTC; i += 64) rs[i] = root[i];
    __syncthreads();

    int idx = blockIdx.x * 64 + threadIdx.x;
    int b = idx >> 12;
    int n = idx & (NN - 1);

    float x[INC];
    #pragma unroll
    for (int c = 0; c < ACc; ++c) x[c] = a[(b * ACc + c) * NN + n];
    #pragma unroll
    for (int c = 0; c < UCc; ++c) x[ACc + c] = u[(b * UCc + c) * NN + n];

    bool first = (b == 0);
    float inv = 0.0f;
    if (first) inv = 1.0f / fmaxf(cnt[n], 1.0f);

    for (int o = 0; o < OUTC; ++o) {
        float v = first ? agg[n * OUTC + o] * inv : 0.0f;
        #pragma unroll
        for (int i = 0; i < INC; ++i) v += x[i] * rs[i * OUTC + o];
        out[(b * OUTC + o) * NN + n] = v;
    }
}

extern "C" void kernel_launch(void* const* d_in, const int* in_sizes, int n_in,
                              void* d_out, int out_size, void* d_ws, size_t ws_size,
                              hipStream_t stream) {
    const float* a    = (const float*)d_in[0];
    const float* u    = (const float*)d_in[1];
    const float* gpos = (const float*)d_in[2];
    const int*   ei   = (const int*)d_in[3];
    const float* w1   = (const float*)d_in[4];
    const float* b1   = (const float*)d_in[5];
    const float* w2   = (const float*)d_in[6];
    const float* b2   = (const float*)d_in[7];
    const float* root = (const float*)d_in[8];
    float* out = (float*)d_out;

    float* ws = (float*)d_ws;

    // fast-path workspace layout (floats):
    //   hs    [0,           +32768)
    //   hd    [32768,       +32768)
    //   rec   [65536,       +1179648)
    //   agg   [1245184,     +131072)
    //   icnt  [1376256,     +4096)     (int)
    //   rowptr[1380352,     +4097)     (int)
    //   woff  [1384449,     +4096)     (int)
    //   slist [1388545,     +32768)    (int)
    const size_t need_fast = (size_t)(1388545 + EE) * sizeof(float);  // ~5.69 MB

    if (ws_size >= need_fast) {
        float* hs  = ws;
        float* hd  = ws + 32768;
        float* rec = ws + 65536;
        float* agg = ws + 1245184;
        int* icnt   = (int*)(ws + 1376256);
        int* rowptr = (int*)(ws + 1380352);
        int* woff   = (int*)(ws + 1384449);
        int* slist  = (int*)(ws + 1388545);

        hipMemsetAsync(icnt, 0, NN * sizeof(int), stream);
        node_hist_kernel<<<640, 256, 0, stream>>>(
            a, u, gpos, ei, w1, b1, w2, b2, hs, hd, rec, icnt);
        scan_kernel<<<1, 256, 0, stream>>>(icnt, rowptr, woff);
        scatter_kernel<<<EE / 256, 256, 0, stream>>>(ei, woff, slist);
        gather_kernel<<<NN / 4, 256, 0, stream>>>(rowptr, slist, hs, hd, rec, agg);
        out_kernel<<<NB * 32 * 16 / 4, 256, 0, stream>>>(a, u, root, agg, out);
    } else {
        float* agg = ws;
        float* cnt = ws + NN * OUTC;
        hipMemsetAsync(d_ws, 0, (size_t)(NN * OUTC + NN) * sizeof(float), stream);
        edge_slow_kernel<<<EE / 256, 256, 0, stream>>>(
            a, u, gpos, ei, w1, b1, w2, b2, agg, cnt);
        out_fallback_kernel<<<(NB * NN) / 64, 64, 0, stream>>>(
            a, u, root, agg, cnt, out);
    }
}